// Round 2
// baseline (76.409 us; speedup 1.0000x reference)
//
#include <hip/hip_runtime.h>

#define IMG    512
#define WT     8            // output columns per lane
#define COLS   16           // WT + 8 halo columns per lane (4 float4)
#define BAND   8            // output rows per wave
#define NBATCH 16
#define NPIX   (16.0 * 512.0 * 512.0)
#define EPS    1e-5f
#define INV81  (1.0f / 81.0f)

// One wave = one 8-row band of one image, full 512-col width.
// lane owns cols [lane*8-4, lane*8+11] (16 cols incl 4-halo each side).
// Vertical 9-sums of {I,J,I2,J2,IJ} live in 80 registers, updated by a
// sliding window (add row y+5, subtract row y-4, old row re-read via L2).
// Horizontal 9-sum is a register sliding window. No LDS, no barriers.
__global__ __launch_bounds__(256) void ncc_band_kernel(
    const float* __restrict__ I, const float* __restrict__ J,
    double* __restrict__ acc)
{
    const int lane = threadIdx.x & 63;
    const int wid  = threadIdx.x >> 6;
    const int band = blockIdx.x * 4 + wid;        // 0..1023
    const int img  = band >> 6;                   // 64 bands / image
    const int y0   = (band & 63) * BAND;

    const float* Ib = I + (size_t)img * IMG * IMG;
    const float* Jb = J + (size_t)img * IMG * IMG;

    const int cb = lane * WT - 4;                 // first halo col

    // per-float4-group column masks (compile-time 4 groups)
    bool inb[4];
    int  coff[4];
    #pragma unroll
    for (int j = 0; j < 4; ++j) {
        int cs = cb + 4 * j;
        inb[j]  = (cs >= 0) && (cs + 3 < IMG);    // groups are fully in or out
        coff[j] = inb[j] ? cs : 0;                // clamped -> always-safe addr
    }

    auto load_row = [&](int y, float4 vi[4], float4 vj[4]) {
        if (y < 0 || y >= IMG) {                  // wave-uniform branch
            #pragma unroll
            for (int j = 0; j < 4; ++j) {
                vi[j] = float4{0.f, 0.f, 0.f, 0.f};
                vj[j] = float4{0.f, 0.f, 0.f, 0.f};
            }
            return;
        }
        const float* rI = Ib + (size_t)y * IMG;
        const float* rJ = Jb + (size_t)y * IMG;
        #pragma unroll
        for (int j = 0; j < 4; ++j) {
            float4 a = *(const float4*)(rI + coff[j]);
            float4 b = *(const float4*)(rJ + coff[j]);
            if (!inb[j]) { a = float4{0.f,0.f,0.f,0.f}; b = float4{0.f,0.f,0.f,0.f}; }
            vi[j] = a; vj[j] = b;
        }
    };

    // vertical running sums (registers, fully unrolled indexing)
    float sI[COLS], sJ[COLS], sII[COLS], sJJ[COLS], sIJ[COLS];
    #pragma unroll
    for (int c = 0; c < COLS; ++c) { sI[c]=0.f; sJ[c]=0.f; sII[c]=0.f; sJJ[c]=0.f; sIJ[c]=0.f; }

    // warm-up: rows y0-4 .. y0+4
    #pragma unroll
    for (int r = -4; r <= 4; ++r) {
        float4 vi[4], vj[4];
        load_row(y0 + r, vi, vj);
        #pragma unroll
        for (int j = 0; j < 4; ++j) {
            const float* a = (const float*)&vi[j];
            const float* b = (const float*)&vj[j];
            #pragma unroll
            for (int e = 0; e < 4; ++e) {
                int c = 4 * j + e;
                float x = a[e], y2 = b[e];
                sI [c] += x;
                sJ [c] += y2;
                sII[c] = fmaf(x,  x,  sII[c]);
                sJJ[c] = fmaf(y2, y2, sJJ[c]);
                sIJ[c] = fmaf(x,  y2, sIJ[c]);
            }
        }
    }

    float local = 0.0f;

    #pragma unroll
    for (int orow = 0; orow < BAND; ++orow) {
        // prefetch slide rows (used after the horizontal pass)
        float4 ni[4], nj[4], oi[4], oj[4];
        if (orow < BAND - 1) {
            load_row(y0 + orow + 5, ni, nj);   // new row entering window
            load_row(y0 + orow - 4, oi, oj);   // old row leaving window
        }

        // horizontal sliding 9-window over the 16 column sums
        float wI = 0.f, wJ = 0.f, wII = 0.f, wJJ = 0.f, wIJ = 0.f;
        #pragma unroll
        for (int c = 0; c < 9; ++c) {
            wI += sI[c]; wJ += sJ[c]; wII += sII[c]; wJJ += sJJ[c]; wIJ += sIJ[c];
        }
        #pragma unroll
        for (int k = 0; k < WT; ++k) {
            if (k > 0) {
                wI  += sI [k+8] - sI [k-1];
                wJ  += sJ [k+8] - sJ [k-1];
                wII += sII[k+8] - sII[k-1];
                wJJ += sJJ[k+8] - sJJ[k-1];
                wIJ += sIJ[k+8] - sIJ[k-1];
            }
            float uI = wI * INV81;
            float uJ = wJ * INV81;
            float cross = fmaf(-uI, wJ, wIJ);   // IJ - I*J/81
            float Iv    = fmaf(-uI, wI, wII);   // I2 - I*I/81
            float Jv    = fmaf(-uJ, wJ, wJJ);   // J2 - J*J/81
            cross = fmaxf(cross, EPS);
            Iv    = fmaxf(Iv,    EPS);
            Jv    = fmaxf(Jv,    EPS);
            local += (cross * cross) * __builtin_amdgcn_rcpf(Iv * Jv);
        }

        // slide vertical window: += new row, -= old row
        if (orow < BAND - 1) {
            #pragma unroll
            for (int j = 0; j < 4; ++j) {
                const float* na = (const float*)&ni[j];
                const float* nb = (const float*)&nj[j];
                const float* oa = (const float*)&oi[j];
                const float* ob = (const float*)&oj[j];
                #pragma unroll
                for (int e = 0; e < 4; ++e) {
                    int c = 4 * j + e;
                    float nx = na[e], ny = nb[e];
                    float ox = oa[e], oy = ob[e];
                    sI [c] += nx - ox;
                    sJ [c] += ny - oy;
                    sII[c] = fmaf(nx, nx, fmaf(-ox, ox, sII[c]));
                    sJJ[c] = fmaf(ny, ny, fmaf(-oy, oy, sJJ[c]));
                    sIJ[c] = fmaf(nx, ny, fmaf(-ox, oy, sIJ[c]));
                }
            }
        }
    }

    // wave reduction + one double atomic per wave
    #pragma unroll
    for (int off = 32; off > 0; off >>= 1)
        local += __shfl_down(local, off, 64);
    if (lane == 0)
        atomicAdd(acc, (double)local);
}

__global__ void ncc_finalize_kernel(const double* __restrict__ acc,
                                    float* __restrict__ out)
{
    out[0] = (float)(-acc[0] / NPIX);
}

extern "C" void kernel_launch(void* const* d_in, const int* in_sizes, int n_in,
                              void* d_out, int out_size, void* d_ws, size_t ws_size,
                              hipStream_t stream)
{
    const float* I = (const float*)d_in[0];   // y_true
    const float* J = (const float*)d_in[1];   // y_pred
    float* out = (float*)d_out;
    double* acc = (double*)d_ws;

    hipMemsetAsync(acc, 0, sizeof(double), stream);

    // 1024 bands (16 images x 64 bands), 4 waves per block -> 256 blocks
    ncc_band_kernel<<<256, 256, 0, stream>>>(I, J, acc);
    ncc_finalize_kernel<<<1, 1, 0, stream>>>(acc, out);
}

// Round 3
// 35.641 us; speedup vs baseline: 2.1439x; 2.1439x over previous
//
#include <hip/hip_runtime.h>

#define IMG    512
#define BAND   8            // output rows per wave
#define NPIX   (16.0 * 512.0 * 512.0)
#define EPS    1e-5f
#define INV81  (1.0f / 81.0f)

struct Rows { float4 i0, i1, j0, j1; };

__device__ __forceinline__ Rows load_rows(const float* __restrict__ Ib,
                                          const float* __restrict__ Jb,
                                          int y, int col0)
{
    Rows r;
    if (y >= 0 && y < IMG) {          // wave-uniform (y0 uniform per wave)
        const float* rI = Ib + (size_t)y * IMG + col0;
        const float* rJ = Jb + (size_t)y * IMG + col0;
        r.i0 = *(const float4*)(rI);
        r.i1 = *(const float4*)(rI + 4);
        r.j0 = *(const float4*)(rJ);
        r.j1 = *(const float4*)(rJ + 4);
    } else {
        r.i0 = r.i1 = r.j0 = r.j1 = float4{0.f, 0.f, 0.f, 0.f};
    }
    return r;
}

// warm-up accumulate (add-only)
#define ACC(c, xv, yv)                          \
    sI[c]  += (xv); sJ[c] += (yv);              \
    sII[c]  = fmaf((xv), (xv), sII[c]);         \
    sJJ[c]  = fmaf((yv), (yv), sJJ[c]);         \
    sIJ[c]  = fmaf((xv), (yv), sIJ[c]);

// sliding update: add new row element, subtract old row element
#define UPD(c, nx, ny, ox, oy)                                  \
    sI[c]  += (nx) - (ox);                                      \
    sJ[c]  += (ny) - (oy);                                      \
    sII[c]  = fmaf((nx), (nx), fmaf(-(ox), (ox), sII[c]));      \
    sJJ[c]  = fmaf((ny), (ny), fmaf(-(oy), (oy), sJJ[c]));      \
    sIJ[c]  = fmaf((nx), (ny), fmaf(-(ox), (oy), sIJ[c]));

#define ACC_ROWS(w)                              \
    ACC(0, w.i0.x, w.j0.x) ACC(1, w.i0.y, w.j0.y)\
    ACC(2, w.i0.z, w.j0.z) ACC(3, w.i0.w, w.j0.w)\
    ACC(4, w.i1.x, w.j1.x) ACC(5, w.i1.y, w.j1.y)\
    ACC(6, w.i1.z, w.j1.z) ACC(7, w.i1.w, w.j1.w)

#define UPD_ROWS(nw, od)                                                  \
    UPD(0, nw.i0.x, nw.j0.x, od.i0.x, od.j0.x)                            \
    UPD(1, nw.i0.y, nw.j0.y, od.i0.y, od.j0.y)                            \
    UPD(2, nw.i0.z, nw.j0.z, od.i0.z, od.j0.z)                            \
    UPD(3, nw.i0.w, nw.j0.w, od.i0.w, od.j0.w)                            \
    UPD(4, nw.i1.x, nw.j1.x, od.i1.x, od.j1.x)                            \
    UPD(5, nw.i1.y, nw.j1.y, od.i1.y, od.j1.y)                            \
    UPD(6, nw.i1.z, nw.j1.z, od.i1.z, od.j1.z)                            \
    UPD(7, nw.i1.w, nw.j1.w, od.i1.w, od.j1.w)

// One wave = one 8-row band, full 512-col width; lane owns 8 output cols
// (no halo loads). Vertical 9-sums of {I,J,I2,J2,IJ} in 40 registers,
// slid down by add-new/sub-old (old row re-read via L2). Horizontal 9-sum:
// halo column-sums come from neighbor LANES via shuffle (lane 0/63 masked
// to zero == image zero-padding), then a register sliding window.
// No LDS tiles, no barriers, prefetch one row-iteration ahead.
__global__ __launch_bounds__(256) void ncc_band_kernel(
    const float* __restrict__ I, const float* __restrict__ J,
    double* __restrict__ acc)
{
    const int lane = threadIdx.x & 63;
    const int wid  = threadIdx.x >> 6;
    const int band = blockIdx.x * 4 + wid;        // 0..1023 (4 adjacent bands/block)
    const int img  = band >> 6;
    const int y0   = (band & 63) * BAND;
    const int col0 = lane * 8;

    const float* Ib = I + (size_t)img * IMG * IMG;
    const float* Jb = J + (size_t)img * IMG * IMG;

    float sI[8], sJ[8], sII[8], sJJ[8], sIJ[8];
    #pragma unroll
    for (int c = 0; c < 8; ++c) { sI[c]=0.f; sJ[c]=0.f; sII[c]=0.f; sJJ[c]=0.f; sIJ[c]=0.f; }

    // ---- warm-up: rows y0-4 .. y0+4 ----
    for (int r = -4; r <= 4; ++r) {
        Rows w = load_rows(Ib, Jb, y0 + r, col0);
        ACC_ROWS(w)
    }

    float local = 0.0f;

    // halo column-sums from neighbor lanes
    auto halo = [&](const float s[8], float l[4], float r[4]) {
        #pragma unroll
        for (int i = 0; i < 4; ++i) {
            float lv = __shfl_up(s[4 + i], 1, 64);
            float rv = __shfl_down(s[i],   1, 64);
            l[i] = (lane == 0)  ? 0.f : lv;   // off left image edge -> 0
            r[i] = (lane == 63) ? 0.f : rv;   // off right image edge -> 0
        }
    };

    // horizontal sliding 9-window + per-pixel cc for one output row
    auto hpass = [&]() {
        float lI[4], rI[4], lJ[4], rJ[4], lII[4], rII[4],
              lJJ[4], rJJ[4], lIJ[4], rIJ[4];
        halo(sI, lI, rI);   halo(sJ, lJ, rJ);   halo(sII, lII, rII);
        halo(sJJ, lJJ, rJJ); halo(sIJ, lIJ, rIJ);

        auto ext = [](const float s[8], const float l[4], const float r[4],
                      int c) -> float {
            return (c < 0) ? l[c + 4] : ((c < 8) ? s[c] : r[c - 8]);
        };

        float wI = 0.f, wJ = 0.f, wII = 0.f, wJJ = 0.f, wIJ = 0.f;
        #pragma unroll
        for (int c = -4; c <= 4; ++c) {
            wI  += ext(sI,  lI,  rI,  c);
            wJ  += ext(sJ,  lJ,  rJ,  c);
            wII += ext(sII, lII, rII, c);
            wJJ += ext(sJJ, lJJ, rJJ, c);
            wIJ += ext(sIJ, lIJ, rIJ, c);
        }
        #pragma unroll
        for (int k = 0; k < 8; ++k) {
            if (k > 0) {
                wI  += ext(sI,  lI,  rI,  k + 4) - ext(sI,  lI,  rI,  k - 5);
                wJ  += ext(sJ,  lJ,  rJ,  k + 4) - ext(sJ,  lJ,  rJ,  k - 5);
                wII += ext(sII, lII, rII, k + 4) - ext(sII, lII, rII, k - 5);
                wJJ += ext(sJJ, lJJ, rJJ, k + 4) - ext(sJJ, lJJ, rJJ, k - 5);
                wIJ += ext(sIJ, lIJ, rIJ, k + 4) - ext(sIJ, lIJ, rIJ, k - 5);
            }
            float uI = wI * INV81;
            float uJ = wJ * INV81;
            float cross = fmaf(-uI, wJ, wIJ);
            float Iv    = fmaf(-uI, wI, wII);
            float Jv    = fmaf(-uJ, wJ, wJJ);
            cross = fmaxf(cross, EPS);
            Iv    = fmaxf(Iv,    EPS);
            Jv    = fmaxf(Jv,    EPS);
            local += (cross * cross) * __builtin_amdgcn_rcpf(Iv * Jv);
        }
    };

    // ---- main loop: 8 output rows, transitions t=0..6 use rows
    //      new = y0+5+t, old = y0-4+t. 2-deep ping-pong prefetch. ----
    Rows nw0 = load_rows(Ib, Jb, y0 + 5, col0);
    Rows od0 = load_rows(Ib, Jb, y0 - 4, col0);
    Rows nw1 = {}, od1 = {};

    for (int ot = 0; ot < 4; ++ot) {
        // orow = 2*ot
        if (ot < 3) {                                  // prefetch trans 2*ot+1
            nw1 = load_rows(Ib, Jb, y0 + 6 + 2 * ot, col0);
            od1 = load_rows(Ib, Jb, y0 - 3 + 2 * ot, col0);
        }
        hpass();
        UPD_ROWS(nw0, od0)                             // trans 2*ot (<=6 always)

        // orow = 2*ot + 1
        if (ot < 3) {                                  // prefetch trans 2*ot+2
            nw0 = load_rows(Ib, Jb, y0 + 7 + 2 * ot, col0);
            od0 = load_rows(Ib, Jb, y0 - 2 + 2 * ot, col0);
        }
        hpass();
        if (ot < 3) { UPD_ROWS(nw1, od1) }             // trans 2*ot+1 (skip t=7)
    }

    // ---- wave reduction + one double atomic per wave ----
    #pragma unroll
    for (int off = 32; off > 0; off >>= 1)
        local += __shfl_down(local, off, 64);
    if (lane == 0)
        atomicAdd(acc, (double)local);
}

__global__ void ncc_finalize_kernel(const double* __restrict__ acc,
                                    float* __restrict__ out)
{
    out[0] = (float)(-acc[0] / NPIX);
}

extern "C" void kernel_launch(void* const* d_in, const int* in_sizes, int n_in,
                              void* d_out, int out_size, void* d_ws, size_t ws_size,
                              hipStream_t stream)
{
    const float* I = (const float*)d_in[0];   // y_true
    const float* J = (const float*)d_in[1];   // y_pred
    float* out = (float*)d_out;
    double* acc = (double*)d_ws;

    hipMemsetAsync(acc, 0, sizeof(double), stream);

    // 1024 bands (16 images x 64 bands of 8 rows), 4 waves/block -> 256 blocks
    ncc_band_kernel<<<256, 256, 0, stream>>>(I, J, acc);
    ncc_finalize_kernel<<<1, 1, 0, stream>>>(acc, out);
}

// Round 4
// 20.446 us; speedup vs baseline: 3.7371x; 1.7432x over previous
//
#include <hip/hip_runtime.h>

#define IMG    512
#define BAND   4            // output rows per wave
#define NBANDS 2048         // 16 images x 128 bands
#define NPIX   (16.0 * 512.0 * 512.0)
#define EPS    1e-5f
#define INV81  (1.0f / 81.0f)

struct Rows { float4 i0, i1, j0, j1; };

__device__ __forceinline__ Rows load_rows(const float* __restrict__ Ib,
                                          const float* __restrict__ Jb,
                                          int y, int col0)
{
    Rows r;
    if (y >= 0 && y < IMG) {          // wave-uniform (y0 uniform per wave)
        const float* rI = Ib + (size_t)y * IMG + col0;
        const float* rJ = Jb + (size_t)y * IMG + col0;
        r.i0 = *(const float4*)(rI);
        r.i1 = *(const float4*)(rI + 4);
        r.j0 = *(const float4*)(rJ);
        r.j1 = *(const float4*)(rJ + 4);
    } else {
        r.i0 = r.i1 = r.j0 = r.j1 = float4{0.f, 0.f, 0.f, 0.f};
    }
    return r;
}

// warm-up accumulate (add-only)
#define ACC(c, xv, yv)                          \
    sI[c]  += (xv); sJ[c] += (yv);              \
    sII[c]  = fmaf((xv), (xv), sII[c]);         \
    sJJ[c]  = fmaf((yv), (yv), sJJ[c]);         \
    sIJ[c]  = fmaf((xv), (yv), sIJ[c]);

// sliding update: add new row element, subtract old row element
#define UPD(c, nx, ny, ox, oy)                                  \
    sI[c]  += (nx) - (ox);                                      \
    sJ[c]  += (ny) - (oy);                                      \
    sII[c]  = fmaf((nx), (nx), fmaf(-(ox), (ox), sII[c]));      \
    sJJ[c]  = fmaf((ny), (ny), fmaf(-(oy), (oy), sJJ[c]));      \
    sIJ[c]  = fmaf((nx), (ny), fmaf(-(ox), (oy), sIJ[c]));

#define ACC_ROWS(w)                              \
    ACC(0, w.i0.x, w.j0.x) ACC(1, w.i0.y, w.j0.y)\
    ACC(2, w.i0.z, w.j0.z) ACC(3, w.i0.w, w.j0.w)\
    ACC(4, w.i1.x, w.j1.x) ACC(5, w.i1.y, w.j1.y)\
    ACC(6, w.i1.z, w.j1.z) ACC(7, w.i1.w, w.j1.w)

#define UPD_ROWS(nw, od)                                                  \
    UPD(0, nw.i0.x, nw.j0.x, od.i0.x, od.j0.x)                            \
    UPD(1, nw.i0.y, nw.j0.y, od.i0.y, od.j0.y)                            \
    UPD(2, nw.i0.z, nw.j0.z, od.i0.z, od.j0.z)                            \
    UPD(3, nw.i0.w, nw.j0.w, od.i0.w, od.j0.w)                            \
    UPD(4, nw.i1.x, nw.j1.x, od.i1.x, od.j1.x)                            \
    UPD(5, nw.i1.y, nw.j1.y, od.i1.y, od.j1.y)                            \
    UPD(6, nw.i1.z, nw.j1.z, od.i1.z, od.j1.z)                            \
    UPD(7, nw.i1.w, nw.j1.w, od.i1.w, od.j1.w)

// One wave = one 4-row band, full 512-col width; lane owns 8 output cols.
// Vertical 9-sums of {I,J,I2,J2,IJ} in 40 registers, slid by add-new/
// sub-old (old row re-read -> L2/L3 hit; whole input fits in L3).
// Horizontal halo column-sums via lane shuffles (lane 0/63 masked = image
// zero-padding). 2048 waves = 2 waves/SIMD. Partial -> private ws slot.
__global__ __launch_bounds__(256) void ncc_band_kernel(
    const float* __restrict__ I, const float* __restrict__ J,
    double* __restrict__ slots)
{
    const int lane = threadIdx.x & 63;
    const int wid  = threadIdx.x >> 6;
    const int band = blockIdx.x * 4 + wid;        // 0..2047
    const int img  = band >> 7;                   // 128 bands / image
    const int y0   = (band & 127) * BAND;
    const int col0 = lane * 8;

    const float* Ib = I + (size_t)img * IMG * IMG;
    const float* Jb = J + (size_t)img * IMG * IMG;

    float sI[8], sJ[8], sII[8], sJJ[8], sIJ[8];
    #pragma unroll
    for (int c = 0; c < 8; ++c) { sI[c]=0.f; sJ[c]=0.f; sII[c]=0.f; sJJ[c]=0.f; sIJ[c]=0.f; }

    // ---- warm-up: rows y0-4 .. y0+4 ----
    for (int r = -4; r <= 4; ++r) {
        Rows w = load_rows(Ib, Jb, y0 + r, col0);
        ACC_ROWS(w)
    }

    float local = 0.0f;

    // halo column-sums from neighbor lanes
    auto halo = [&](const float s[8], float l[4], float r[4]) {
        #pragma unroll
        for (int i = 0; i < 4; ++i) {
            float lv = __shfl_up(s[4 + i], 1, 64);
            float rv = __shfl_down(s[i],   1, 64);
            l[i] = (lane == 0)  ? 0.f : lv;   // off left image edge -> 0
            r[i] = (lane == 63) ? 0.f : rv;   // off right image edge -> 0
        }
    };

    // horizontal sliding 9-window + per-pixel cc for one output row
    auto hpass = [&]() {
        float lI[4], rI[4], lJ[4], rJ[4], lII[4], rII[4],
              lJJ[4], rJJ[4], lIJ[4], rIJ[4];
        halo(sI, lI, rI);   halo(sJ, lJ, rJ);   halo(sII, lII, rII);
        halo(sJJ, lJJ, rJJ); halo(sIJ, lIJ, rIJ);

        auto ext = [](const float s[8], const float l[4], const float r[4],
                      int c) -> float {
            return (c < 0) ? l[c + 4] : ((c < 8) ? s[c] : r[c - 8]);
        };

        float wI = 0.f, wJ = 0.f, wII = 0.f, wJJ = 0.f, wIJ = 0.f;
        #pragma unroll
        for (int c = -4; c <= 4; ++c) {
            wI  += ext(sI,  lI,  rI,  c);
            wJ  += ext(sJ,  lJ,  rJ,  c);
            wII += ext(sII, lII, rII, c);
            wJJ += ext(sJJ, lJJ, rJJ, c);
            wIJ += ext(sIJ, lIJ, rIJ, c);
        }
        #pragma unroll
        for (int k = 0; k < 8; ++k) {
            if (k > 0) {
                wI  += ext(sI,  lI,  rI,  k + 4) - ext(sI,  lI,  rI,  k - 5);
                wJ  += ext(sJ,  lJ,  rJ,  k + 4) - ext(sJ,  lJ,  rJ,  k - 5);
                wII += ext(sII, lII, rII, k + 4) - ext(sII, lII, rII, k - 5);
                wJJ += ext(sJJ, lJJ, rJJ, k + 4) - ext(sJJ, lJJ, rJJ, k - 5);
                wIJ += ext(sIJ, lIJ, rIJ, k + 4) - ext(sIJ, lIJ, rIJ, k - 5);
            }
            float uI = wI * INV81;
            float uJ = wJ * INV81;
            float cross = fmaf(-uI, wJ, wIJ);
            float Iv    = fmaf(-uI, wI, wII);
            float Jv    = fmaf(-uJ, wJ, wJJ);
            cross = fmaxf(cross, EPS);
            Iv    = fmaxf(Iv,    EPS);
            Jv    = fmaxf(Jv,    EPS);
            local += (cross * cross) * __builtin_amdgcn_rcpf(Iv * Jv);
        }
    };

    // ---- main loop: 4 output rows, transitions t=0..2
    //      (new = y0+5+t, old = y0-4+t), loads issued >=1 hpass ahead ----
    Rows nw0 = load_rows(Ib, Jb, y0 + 5, col0);
    Rows od0 = load_rows(Ib, Jb, y0 - 4, col0);
    Rows nw1 = load_rows(Ib, Jb, y0 + 6, col0);
    Rows od1 = load_rows(Ib, Jb, y0 - 3, col0);

    hpass();                               // row y0
    UPD_ROWS(nw0, od0)
    nw0 = load_rows(Ib, Jb, y0 + 7, col0);
    od0 = load_rows(Ib, Jb, y0 - 2, col0);
    hpass();                               // row y0+1
    UPD_ROWS(nw1, od1)
    hpass();                               // row y0+2
    UPD_ROWS(nw0, od0)
    hpass();                               // row y0+3

    // ---- wave reduction + private slot write (no atomic, no init) ----
    #pragma unroll
    for (int off = 32; off > 0; off >>= 1)
        local += __shfl_down(local, off, 64);
    if (lane == 0)
        slots[band] = (double)local;
}

__global__ __launch_bounds__(256) void ncc_finalize_kernel(
    const double* __restrict__ slots, float* __restrict__ out)
{
    const int tid = threadIdx.x;
    double t = 0.0;
    #pragma unroll
    for (int i = 0; i < NBANDS / 256; ++i)
        t += slots[tid + i * 256];
    #pragma unroll
    for (int off = 32; off > 0; off >>= 1)
        t += __shfl_down(t, off, 64);

    __shared__ double wsum[4];
    if ((tid & 63) == 0) wsum[tid >> 6] = t;
    __syncthreads();
    if (tid == 0)
        out[0] = (float)(-(wsum[0] + wsum[1] + wsum[2] + wsum[3]) / NPIX);
}

extern "C" void kernel_launch(void* const* d_in, const int* in_sizes, int n_in,
                              void* d_out, int out_size, void* d_ws, size_t ws_size,
                              hipStream_t stream)
{
    const float* I = (const float*)d_in[0];   // y_true
    const float* J = (const float*)d_in[1];   // y_pred
    float* out = (float*)d_out;
    double* slots = (double*)d_ws;            // 2048 doubles, all written each call

    // 2048 bands (16 images x 128 bands of 4 rows), 4 waves/block -> 512 blocks
    ncc_band_kernel<<<512, 256, 0, stream>>>(I, J, slots);
    ncc_finalize_kernel<<<1, 256, 0, stream>>>(slots, out);
}